// Round 5
// baseline (5514.356 us; speedup 1.0000x reference)
//
#include <hip/hip_runtime.h>

typedef float f32x2 __attribute__((ext_vector_type(2)));

// ---------------------------------------------------------------------------
// VOP3P packed f32 (2 f32 ops per instruction per lane). Same IEEE f32 RN
// rounding per element as the scalar ops they replace.
// ---------------------------------------------------------------------------
__device__ __forceinline__ f32x2 pk_add(f32x2 a, f32x2 b) {
    f32x2 d; asm("v_pk_add_f32 %0, %1, %2" : "=v"(d) : "v"(a), "v"(b)); return d;
}
__device__ __forceinline__ f32x2 pk_mul(f32x2 a, f32x2 b) {
    f32x2 d; asm("v_pk_mul_f32 %0, %1, %2" : "=v"(d) : "v"(a), "v"(b)); return d;
}
__device__ __forceinline__ f32x2 pk_fma(f32x2 a, f32x2 b, f32x2 c) {
    f32x2 d; asm("v_pk_fma_f32 %0, %1, %2, %3" : "=v"(d) : "v"(a), "v"(b), "v"(c)); return d;
}

// ---------------------------------------------------------------------------
// Strict f64 squared distance matching numpy float64:
//   d = ((dx*dx + dy*dy) + dz*dz), every op individually rounded, no FMA.
// ---------------------------------------------------------------------------
__device__ __forceinline__ double dist2d(float x, float y, float z,
                                         double px, double py, double pz) {
    double dx = __dsub_rn((double)x, px);
    double dy = __dsub_rn((double)y, py);
    double dz = __dsub_rn((double)z, pz);
    double a  = __dmul_rn(dx, dx);
    double b  = __dmul_rn(dy, dy);
    double c  = __dmul_rn(dz, dz);
    return __dadd_rn(__dadd_rn(a, b), c);
}

// DPP move; lanes with invalid source keep their own value (bound_ctrl=false).
template <int CTRL>
__device__ __forceinline__ unsigned dpp_u32_keep(unsigned v) {
    return (unsigned)__builtin_amdgcn_update_dpp((int)v, (int)v, CTRL, 0xF, 0xF, false);
}

// After this, lane 63 holds umax over all 64 lanes.
__device__ __forceinline__ unsigned wave_umax64(unsigned v) {
    v = max(v, dpp_u32_keep<0x111>(v));  // row_shr:1
    v = max(v, dpp_u32_keep<0x112>(v));  // row_shr:2
    v = max(v, dpp_u32_keep<0x114>(v));  // row_shr:4
    v = max(v, dpp_u32_keep<0x118>(v));  // row_shr:8
    v = max(v, dpp_u32_keep<0x142>(v));  // row_bcast:15
    v = max(v, dpp_u32_keep<0x143>(v));  // row_bcast:31
    return v;
}

__device__ __forceinline__ float readlane_f32(float v, int l) {
    return __int_as_float(__builtin_amdgcn_readlane(__float_as_int(v), l));
}

// Among lanes in mask (nonempty): all hold equal hi; pick max lo, then min idx.
// Fast path when unique. Mask strictly shrinks -> terminates (<=64 iters).
__device__ __forceinline__ int pick_lane(unsigned long long m, unsigned lo, int idx) {
    if (__popcll(m) == 1) return __ffsll(m) - 1;
    unsigned bl = 0; int bidx = 0x7FFFFFFF; int ml = -1;
    unsigned long long t = m;
    while (t) {
        int l = __ffsll(t) - 1;
        unsigned lol = (unsigned)__builtin_amdgcn_readlane((int)lo, l);
        int      il  = __builtin_amdgcn_readlane(idx, l);
        if (ml < 0 || lol > bl || (lol == bl && il < bidx)) { bl = lol; bidx = il; ml = l; }
        t &= t - 1;
    }
    return ml;
}

// ---------------------------------------------------------------------------
// FPS. One block per batch. Point p = j*NT + tid, j < PPT, n_in = PPT*NT.
//
// Exactness: md is f64, bit-matching numpy float64 (dist2d). md >= 0, and for
// non-negative IEEE doubles value order == integer order of (hi32, lo32), so
// all max machinery runs on u32 hi-words (v_max_u32 DPP); exact hi-ties fall
// to pick_lane resolving (lo desc, idx asc). argmax tie-break = min index.
//
// SPECULATIVE DOUBLE-SELECTION (2 picks per barrier convoy when provably
// exact): after selecting p1 = argmax(md) (value M1), all other points have
// md <= M2 (exact global second max) and updates only DECREASE md. Hence the
// next pick is the first-index M2-holder i2 IFF d(i2,p1)^2 >= M2 (exact f64
// compare): its md is untouched, everything else stays <= M2, and min-index
// tie-break is inherited (survivors of the M2-holder set keep index order).
// Guards: fall back to exact single-step when d < M2, when i+1 == npoints,
// or when M1 == 0 or M2 == 0 (degenerate duplicate clouds, where numpy's
// argmax can re-select an index; single-step handles those exactly).
//
// Per-wave state: exact top-1 AND top-2 (value,lo,idx,coords), maintained by
// scan12() + reduce_winner() which run only when stale. Staleness gate:
// md only decreases; keep-first invariants give: top-1 stale iff slot bj
// decreased; top-2 stale iff slot b2j decreased (among j != bj, all j < b2j
// have md[j] < b2v strictly). need = decrease at bj or b2j.
// Phase-2 excludes exactly p1's entry by substituting the winner wave's
// published top-2 for its top-1 in the second reduce.
//
// Parity double-buffer is keyed by a CONVOY counter (always +1) so the
// barrier-separation argument (write[par] at convoy c vs reads[par] at c-2
// separated by barrier at c-1) holds under variable stepping i += 1 or 2.
//
// ZERO global memory ops in the serial loop (LDS history, bulk dump at end).
// Screen: v_pk_* packed f32, per-element rounding identical to scalar form;
// margin 1.000004 >> 3-ulp fma error => screened-out slots provably
// unchanged; md stays bit-exact.
//
// Hang/poison safety: barriers at top-level with block-uniform trip count
// (happy/i are block-uniform: computed redundantly from identical shared
// data); pick_lane masks strictly shrink; NaN/garbage data cannot hang
// (integer compares in reduces; NaN f64/f32 compares are well-defined false);
// all in-loop indexing is LDS with construction-bounded indices.
//
// Only level-1 FPS runs. FPS is nested: FPS on the ordered output of a
// previous FPS selects indices 0,1,2,... bit-exactly (subset-max argument;
// selected points have running dist 0; argmax tie-break = first occurrence).
// So idx2/3/4 are arange() -> identity gathers in the MLP levels.
// ---------------------------------------------------------------------------
template <int PPT, int NT>
__global__ __launch_bounds__(NT, 4) void fps_kernel(
    const float* __restrict__ pts,  // [B][n_in][stride], xyz at channels 0..2
    int stride, int npoints,
    int* __restrict__ idx_out)      // [B][npoints]
{
    constexpr int NWAVES = NT / 64;
    constexpr int N_IN   = PPT * NT;
    constexpr int NPAIR  = PPT / 2;
    constexpr int LOGNT  = (NT == 1024) ? 10 : (NT == 512) ? 9 : 8;

    const int batch = blockIdx.x;
    const int tid   = threadIdx.x;
    const int lane  = tid & 63;
    const int wv    = tid >> 6;

    const float* base = pts + (size_t)batch * N_IN * stride;
    int* iout = idx_out + (size_t)batch * npoints;

    __shared__ uint4  s_pk[2][NWAVES];   // {hi1, idx1, hi2, idx2}
    __shared__ float4 s_c1[2][NWAVES];   // {x1, y1, z1, lo1-as-float}
    __shared__ float4 s_c2[2][NWAVES];   // {x2, y2, z2, lo2-as-float}
    __shared__ int    s_hist[4096];      // npoints <= 4096

    f32x2  pcx[NPAIR], pcy[NPAIR], pcz[NPAIR];
    double md[PPT];
    float  th[PPT];

#pragma unroll
    for (int k = 0; k < NPAIR; ++k) {
        int p0 = (2 * k) * NT + tid;
        int p1 = (2 * k + 1) * NT + tid;
        const float* r0 = base + (size_t)p0 * stride;
        const float* r1 = base + (size_t)p1 * stride;
        pcx[k] = f32x2{r0[0], r1[0]};
        pcy[k] = f32x2{r0[1], r1[1]};
        pcz[k] = f32x2{r0[2], r1[2]};
    }

    // first selected point is index 0
    float q0x = base[0], q0y = base[1], q0z = base[2];
    if (tid == 0) s_hist[0] = 0;

#pragma unroll
    for (int j = 0; j < PPT; ++j) {
        float x = pcx[j / 2][j & 1], y = pcy[j / 2][j & 1], z = pcz[j / 2][j & 1];
        md[j] = dist2d(x, y, z, (double)q0x, (double)q0y, (double)q0z);
        th[j] = __fmul_rn((float)md[j], 1.000004f);
    }

    // per-lane top-1 / top-2 state (keep-first => min slot index on ties)
    double bv = -1.0, b2v = -1.0;
    int    bj = 0,    b2j = 0;
    float  bx = 0.f, by = 0.f, bz = 0.f;
    float  b2x = 0.f, b2y = 0.f, b2z = 0.f;

    auto scan12 = [&]() {
        bv = -1.0; bj = 0;
#pragma unroll
        for (int j = 0; j < PPT; ++j) {
            float x = pcx[j / 2][j & 1], y = pcy[j / 2][j & 1], z = pcz[j / 2][j & 1];
            if (md[j] > bv) { bv = md[j]; bj = j; bx = x; by = y; bz = z; }
        }
        b2v = -1.0; b2j = 0;
#pragma unroll
        for (int j = 0; j < PPT; ++j) {
            float x = pcx[j / 2][j & 1], y = pcy[j / 2][j & 1], z = pcz[j / 2][j & 1];
            if ((j != bj) && (md[j] > b2v)) { b2v = md[j]; b2j = j; b2x = x; b2y = y; b2z = z; }
        }
    };

    // cached wave top-1/top-2 (wave-uniform after reduce_winner)
    unsigned w1hi = 0, w1lo = 0, w2hi = 0, w2lo = 0;
    int      w1i = 0, w2i = 0;
    float    w1x = 0.f, w1y = 0.f, w1z = 0.f, w2x = 0.f, w2y = 0.f, w2z = 0.f;
    bool pub0 = false, pub1 = false;

    auto reduce_winner = [&]() {
        unsigned hi1  = (unsigned)__double2hiint(bv);
        unsigned lo1  = (unsigned)__double2loint(bv);
        int      idx1 = (bj << LOGNT) + tid;
        unsigned mx1 = (unsigned)__builtin_amdgcn_readlane((int)wave_umax64(hi1), 63);
        int wl = pick_lane(__ballot(hi1 == mx1), lo1, idx1);
        w1hi = mx1;
        w1lo = (unsigned)__builtin_amdgcn_readlane((int)lo1, wl);
        w1i  = __builtin_amdgcn_readlane(idx1, wl);
        w1x  = readlane_f32(bx, wl);
        w1y  = readlane_f32(by, wl);
        w1z  = readlane_f32(bz, wl);
        // merged second candidates: winner lane contributes its top-2,
        // all other lanes their top-1 -> wave max excluding only (wl, bj@wl).
        bool sel = (lane == wl);
        unsigned mh  = sel ? (unsigned)__double2hiint(b2v) : hi1;
        unsigned mlo = sel ? (unsigned)__double2loint(b2v) : lo1;
        int      mix = sel ? ((b2j << LOGNT) + tid) : idx1;
        float    mxx = sel ? b2x : bx;
        float    myy = sel ? b2y : by;
        float    mzz = sel ? b2z : bz;
        unsigned mx2 = (unsigned)__builtin_amdgcn_readlane((int)wave_umax64(mh), 63);
        int wl2 = pick_lane(__ballot(mh == mx2), mlo, mix);
        w2hi = mx2;
        w2lo = (unsigned)__builtin_amdgcn_readlane((int)mlo, wl2);
        w2i  = __builtin_amdgcn_readlane(mix, wl2);
        w2x  = readlane_f32(mxx, wl2);
        w2y  = readlane_f32(myy, wl2);
        w2z  = readlane_f32(mzz, wl2);
        pub0 = false; pub1 = false;
    };

    scan12();
    reduce_winner();

    int i = 1, cv = 0;
    while (i < npoints) {
        const int par = cv & 1;
        ++cv;

        // ---- phase 1: publish cached wave top-1/top-2 (skip if current) ----
        bool pubd = par ? pub1 : pub0;
        if (!pubd) {
            if (lane == 0) {
                s_pk[par][wv] = make_uint4(w1hi, (unsigned)w1i, w2hi, (unsigned)w2i);
                s_c1[par][wv] = make_float4(w1x, w1y, w1z, __uint_as_float(w1lo));
                s_c2[par][wv] = make_float4(w2x, w2y, w2z, __uint_as_float(w2lo));
            }
            if (par) pub1 = true; else pub0 = true;
        }
        __syncthreads();   // no outstanding vmem in-loop -> vmcnt drain free

        // ---- phase 2: global top-1 then top-2 (redundant per wave) ----
        const int sl = lane & (NWAVES - 1);
        uint4  pk = s_pk[par][sl];
        float4 c1 = s_c1[par][sl];
        float4 c2 = s_c2[par][sl];

        unsigned v1 = (lane < NWAVES) ? pk.x : 0u;
        v1 = max(v1, dpp_u32_keep<0x111>(v1));
        v1 = max(v1, dpp_u32_keep<0x112>(v1));
        if constexpr (NWAVES >= 8)  v1 = max(v1, dpp_u32_keep<0x114>(v1));
        if constexpr (NWAVES >= 16) v1 = max(v1, dpp_u32_keep<0x118>(v1));
        unsigned ghi1 = (unsigned)__builtin_amdgcn_readlane((int)v1, NWAVES - 1);
        int wlA = pick_lane(__ballot((lane < NWAVES) && (pk.x == ghi1)),
                            (unsigned)__float_as_int(c1.w), (int)pk.y);
        int   i1  = __builtin_amdgcn_readlane((int)pk.y, wlA);
        float q1x = readlane_f32(c1.x, wlA);
        float q1y = readlane_f32(c1.y, wlA);
        float q1z = readlane_f32(c1.z, wlA);
        unsigned g1lo = (unsigned)__builtin_amdgcn_readlane(__float_as_int(c1.w), wlA);

        // merged: winner wave -> its top-2, others -> top-1 (excludes p1 only)
        bool msel = (sl == wlA);
        unsigned mh  = msel ? pk.z : pk.x;
        int      mix = (int)(msel ? pk.w : pk.y);
        float    mlw = msel ? c2.w : c1.w;
        unsigned mlo = (unsigned)__float_as_int(mlw);
        float    mqx = msel ? c2.x : c1.x;
        float    mqy = msel ? c2.y : c1.y;
        float    mqz = msel ? c2.z : c1.z;
        unsigned v2 = (lane < NWAVES) ? mh : 0u;
        v2 = max(v2, dpp_u32_keep<0x111>(v2));
        v2 = max(v2, dpp_u32_keep<0x112>(v2));
        if constexpr (NWAVES >= 8)  v2 = max(v2, dpp_u32_keep<0x114>(v2));
        if constexpr (NWAVES >= 16) v2 = max(v2, dpp_u32_keep<0x118>(v2));
        unsigned ghi2 = (unsigned)__builtin_amdgcn_readlane((int)v2, NWAVES - 1);
        int wlB = pick_lane(__ballot((lane < NWAVES) && (mh == ghi2)), mlo, mix);
        int   i2  = __builtin_amdgcn_readlane(mix, wlB);
        float q2x = readlane_f32(mqx, wlB);
        float q2y = readlane_f32(mqy, wlB);
        float q2z = readlane_f32(mqz, wlB);
        unsigned g2lo = (unsigned)__builtin_amdgcn_readlane((int)mlo, wlB);

        // survive check (exact f64): d(p2,p1)^2 >= M2 -> p2 provably next pick
        const double q1x64 = (double)q1x, q1y64 = (double)q1y, q1z64 = (double)q1z;
        double M2d = __hiloint2double((int)ghi2, (int)g2lo);
        double d12 = dist2d(q2x, q2y, q2z, q1x64, q1y64, q1z64);
        bool happy = (i + 1 < npoints) && (d12 >= M2d)
                     && ((ghi1 | g1lo) != 0u) && ((ghi2 | g2lo) != 0u);

        if (tid == 0) { s_hist[i] = i1; if (happy) s_hist[i + 1] = i2; }

        // ---- screen+update passes ----
        bool need = false;
        auto pass = [&](float qx, float qy, float qz) {
            const double px = (double)qx, py = (double)qy, pz = (double)qz;
            const f32x2 nqx = {-qx, -qx}, nqy = {-qy, -qy}, nqz = {-qz, -qz};
            int fmask = 0;
#pragma unroll
            for (int k = 0; k < NPAIR; ++k) {
                f32x2 dx = pk_add(pcx[k], nqx);
                f32x2 dy = pk_add(pcy[k], nqy);
                f32x2 dz = pk_add(pcz[k], nqz);
                f32x2 d  = pk_fma(dx, dx, pk_fma(dy, dy, pk_mul(dz, dz)));
                fmask |= (__any(d.x < th[2 * k])     ? (1 << (2 * k))     : 0);
                fmask |= (__any(d.y < th[2 * k + 1]) ? (1 << (2 * k + 1)) : 0);
            }
            if (fmask) {
#pragma unroll
                for (int j = 0; j < PPT; ++j) {
                    if (fmask & (1 << j)) {
                        float x = pcx[j / 2][j & 1], y = pcy[j / 2][j & 1], z = pcz[j / 2][j & 1];
                        double d   = dist2d(x, y, z, px, py, pz);
                        double old = md[j];
                        // stale iff top-1 or top-2 slot decreased (invariant proof)
                        need = need | (((bj == j) | (b2j == j)) & (d < old));
                        md[j] = fmin(old, d);
                        th[j] = __fmul_rn((float)md[j], 1.000004f);
                    }
                }
            }
        };
        pass(q1x, q1y, q1z);
        if (happy) pass(q2x, q2y, q2z);

        if (__any(need)) { scan12(); reduce_winner(); }

        i += happy ? 2 : 1;
    }

    // coalesced bulk dump of the selected indices
    __syncthreads();
    for (int k = tid; k < npoints; k += NT) iout[k] = s_hist[k];
}

// ---------------------------------------------------------------------------
// Gather + 2-layer pointwise MLP + xyz/feat concat, one kernel per level.
// IDENT=true: identity gather (FPS nesting property -> idx == arange).
// ---------------------------------------------------------------------------
template <int CIN, int F, bool REPEAT, bool IDENT>
__global__ __launch_bounds__(256) void mlp_kernel(
    const float* __restrict__ pts, int stride, int n_in,
    const int* __restrict__ idx,
    const float* __restrict__ w1, const float* __restrict__ b1,
    const float* __restrict__ w2, const float* __restrict__ b2,
    float* __restrict__ out, int np)
{
    constexpr int P    = 256 / F;
    constexpr int CINS = REPEAT ? (CIN / 2) : CIN;  // stored input channels
    constexpr int LOGF = (F == 16) ? 4 : (F == 32) ? 5 : (F == 64) ? 6 : 7;

    __shared__ float xs[P][CINS];
    __shared__ float h[P][F];

    const int tid = threadIdx.x;
    const int pl  = tid >> LOGF;       // point within block
    const int c   = tid & (F - 1);     // output channel
    const int b   = blockIdx.y;
    const int pid = blockIdx.x * P + pl;

    const int id = IDENT ? pid : idx[(size_t)b * np + pid];
    const float* row = pts + ((size_t)b * n_in + id) * stride;

    if (c < CINS) xs[pl][c] = row[c];
    __syncthreads();

    float acc = b1[c];
#pragma unroll
    for (int k = 0; k < CIN; ++k) {
        const int xk = REPEAT ? (k % 3) : k;
        acc = fmaf(xs[pl][xk], w1[k * F + c], acc);
    }
    h[pl][c] = fmaxf(acc, 0.0f);
    __syncthreads();

    float acc2 = b2[c];
#pragma unroll
    for (int f = 0; f < F; ++f)
        acc2 = fmaf(h[pl][f], w2[f * F + c], acc2);

    float res = (c < 3) ? xs[pl][c] : acc2;
    out[((size_t)b * np + pid) * (size_t)F + c] = res;
}

// ---------------------------------------------------------------------------
// Launch. Only level-1 FPS is computed; levels 2-4 are identity gathers.
// ---------------------------------------------------------------------------
extern "C" void kernel_launch(void* const* d_in, const int* in_sizes, int n_in_cnt,
                              void* d_out, int out_size, void* d_ws, size_t ws_size,
                              hipStream_t stream) {
    const float* scene = (const float*)d_in[0];
    const float* w1_1 = (const float*)d_in[1];
    const float* b1_1 = (const float*)d_in[2];
    const float* w2_1 = (const float*)d_in[3];
    const float* b2_1 = (const float*)d_in[4];
    const float* w1_2 = (const float*)d_in[5];
    const float* b1_2 = (const float*)d_in[6];
    const float* w2_2 = (const float*)d_in[7];
    const float* b2_2 = (const float*)d_in[8];
    const float* w1_3 = (const float*)d_in[9];
    const float* b1_3 = (const float*)d_in[10];
    const float* w2_3 = (const float*)d_in[11];
    const float* b2_3 = (const float*)d_in[12];
    const float* w1_4 = (const float*)d_in[13];
    const float* b1_4 = (const float*)d_in[14];
    const float* w2_4 = (const float*)d_in[15];
    const float* b2_4 = (const float*)d_in[16];

    float* out  = (float*)d_out;
    float* out1 = out;                 // [8][4096][16]
    float* out2 = out + 524288;        // [8][2048][32]
    float* out3 = out + 1048576;       // [8][1024][64]
    float* out4 = out + 1572864;       // [8][512][128]

    int* idx1 = (int*)d_ws;            // 8*4096 (only level-1 indices needed)

    const int B = 8;

    // Level 1: N=8192 -> 4096, cin=6 (repeat), F=16
    fps_kernel<8, 1024><<<B, 1024, 0, stream>>>(scene, 3, 4096, idx1);
    mlp_kernel<6, 16, true, false><<<dim3(256, B), 256, 0, stream>>>(
        scene, 3, 8192, idx1, w1_1, b1_1, w2_1, b2_1, out1, 4096);

    // Level 2: 4096 -> 2048, cin=16, F=32   (identity gather, no FPS)
    mlp_kernel<16, 32, false, true><<<dim3(256, B), 256, 0, stream>>>(
        out1, 16, 4096, nullptr, w1_2, b1_2, w2_2, b2_2, out2, 2048);

    // Level 3: 2048 -> 1024, cin=32, F=64   (identity gather, no FPS)
    mlp_kernel<32, 64, false, true><<<dim3(256, B), 256, 0, stream>>>(
        out2, 32, 2048, nullptr, w1_3, b1_3, w2_3, b2_3, out3, 1024);

    // Level 4: 1024 -> 512, cin=64, F=128   (identity gather, no FPS)
    mlp_kernel<64, 128, false, true><<<dim3(256, B), 256, 0, stream>>>(
        out3, 64, 1024, nullptr, w1_4, b1_4, w2_4, b2_4, out4, 512);
}

// Round 6
// 5188.540 us; speedup vs baseline: 1.0628x; 1.0628x over previous
//
#include <hip/hip_runtime.h>

typedef float f32x2 __attribute__((ext_vector_type(2)));

// ---------------------------------------------------------------------------
// VOP3P packed f32 (2 f32 ops per instruction per lane). Same IEEE f32 RN
// rounding per element as the scalar ops they replace.
// ---------------------------------------------------------------------------
__device__ __forceinline__ f32x2 pk_add(f32x2 a, f32x2 b) {
    f32x2 d; asm("v_pk_add_f32 %0, %1, %2" : "=v"(d) : "v"(a), "v"(b)); return d;
}
__device__ __forceinline__ f32x2 pk_mul(f32x2 a, f32x2 b) {
    f32x2 d; asm("v_pk_mul_f32 %0, %1, %2" : "=v"(d) : "v"(a), "v"(b)); return d;
}
__device__ __forceinline__ f32x2 pk_fma(f32x2 a, f32x2 b, f32x2 c) {
    f32x2 d; asm("v_pk_fma_f32 %0, %1, %2, %3" : "=v"(d) : "v"(a), "v"(b), "v"(c)); return d;
}

// ---------------------------------------------------------------------------
// Strict f64 squared distance matching numpy float64:
//   d = ((dx*dx + dy*dy) + dz*dz), every op individually rounded, no FMA.
// ---------------------------------------------------------------------------
__device__ __forceinline__ double dist2d(float x, float y, float z,
                                         double px, double py, double pz) {
    double dx = __dsub_rn((double)x, px);
    double dy = __dsub_rn((double)y, py);
    double dz = __dsub_rn((double)z, pz);
    double a  = __dmul_rn(dx, dx);
    double b  = __dmul_rn(dy, dy);
    double c  = __dmul_rn(dz, dz);
    return __dadd_rn(__dadd_rn(a, b), c);
}

// DPP move; lanes with invalid source keep their own value (bound_ctrl=false).
template <int CTRL>
__device__ __forceinline__ unsigned dpp_u32_keep(unsigned v) {
    return (unsigned)__builtin_amdgcn_update_dpp((int)v, (int)v, CTRL, 0xF, 0xF, false);
}

// After this, lane 63 holds umax over all 64 lanes.
__device__ __forceinline__ unsigned wave_umax64(unsigned v) {
    v = max(v, dpp_u32_keep<0x111>(v));  // row_shr:1
    v = max(v, dpp_u32_keep<0x112>(v));  // row_shr:2
    v = max(v, dpp_u32_keep<0x114>(v));  // row_shr:4
    v = max(v, dpp_u32_keep<0x118>(v));  // row_shr:8
    v = max(v, dpp_u32_keep<0x142>(v));  // row_bcast:15
    v = max(v, dpp_u32_keep<0x143>(v));  // row_bcast:31
    return v;
}

__device__ __forceinline__ float readlane_f32(float v, int l) {
    return __int_as_float(__builtin_amdgcn_readlane(__float_as_int(v), l));
}

// Among lanes in mask (nonempty): all hold equal hi; pick max lo, then min idx.
// Fast path when unique. Mask strictly shrinks -> terminates (<=64 iters).
__device__ __forceinline__ int pick_lane(unsigned long long m, unsigned lo, int idx) {
    if (__popcll(m) == 1) return __ffsll(m) - 1;
    unsigned bl = 0; int bidx = 0x7FFFFFFF; int ml = -1;
    unsigned long long t = m;
    while (t) {
        int l = __ffsll(t) - 1;
        unsigned lol = (unsigned)__builtin_amdgcn_readlane((int)lo, l);
        int      il  = __builtin_amdgcn_readlane(idx, l);
        if (ml < 0 || lol > bl || (lol == bl && il < bidx)) { bl = lol; bidx = il; ml = l; }
        t &= t - 1;
    }
    return ml;
}

// ---------------------------------------------------------------------------
// FPS. One block per batch. Point p = j*NT + tid, j < PPT, n_in = PPT*NT.
//
// Exactness: md is f64, bit-matching numpy float64 (dist2d). md >= 0, and for
// non-negative IEEE doubles value order == integer order of (hi32, lo32), so
// all max machinery runs on u32 hi-words (v_max_u32 DPP); exact hi-ties fall
// to pick_lane resolving (lo desc, idx asc). argmax tie-break = min index.
//
// Convoy-overhead optimizations (the serial loop is convoy-latency bound):
//   - phase-2 LDS reads exec-masked to lane<NWAVES: DPP row_shr never crosses
//     16-lane rows, so lanes >=16 never feed the reduce; masking cuts the
//     post-barrier LDS pipe burst ~4x (16 waves all read simultaneously).
//   - per-lane LAZY TOP-2: updates only DECREASE md, so decreases at slots
//     outside {bj,b2j} can never change top-1/top-2. Keep-first invariants
//     (j<bj => md[j]<bv strict; j!=bj, j<b2j => md[j]<b2v strict) give exact
//     fast paths when only bj decreased to dNew:
//        dNew >  b2v: top1 value = dNew, slot keeps (unique max); t2 valid.
//        dNew <  b2v: top1 = (b2v,b2j) incl. min-index ties; t2 dirty.
//        dNew == b2v, or b2j also decreased: rare full scan12.
//     Dirty t2 is rebuilt in the SHADOW of the next phase-2 ds_read latency
//     (register-only work placed between load issue and first use).
//   - winner-lane DIRECT publish: pick_lane yields a unique winner lane which
//     writes s_pk/s_c from its own registers (no readlane extraction). An
//     iwrote flag lets the same lane publish the second parity buffer at a
//     later loop top. Invariant: pub[p]==false ==> the iwrote lane's regs
//     still hold exactly the values belonging in p (any new reduce refreshes
//     regs, iwrote, and both flags).
//   - double-buffered parity: reduce at iter k writes parity (k+1)&1 (its
//     previous readers finished before barrier k); flagged catch-up writes
//     happen at loop top before the barrier. One barrier per iteration.
//   - screen: v_pk_* packed f32, per-element rounding identical to scalar;
//     margin 1.000004 >> 3-ulp fma error => screened-out slots provably
//     unchanged; md stays bit-exact.
//   - ZERO global memory ops in the serial loop (LDS history, bulk dump).
//
// Hang/poison safety: barriers at top-level with block-uniform trip count;
// pick_lane masks strictly shrink; NaN/garbage data cannot hang (integer
// compares in reduces; NaN f64/f32 compares are well-defined false); all
// in-loop indexing is LDS with construction-bounded indices; all per-lane
// arrays are indexed with compile-time constants (no scratch).
//
// Only level-1 FPS runs. FPS is nested: FPS on the ordered output of a
// previous FPS selects indices 0,1,2,... bit-exactly (subset-max argument;
// selected points have running dist 0; argmax tie-break = first occurrence).
// So idx2/3/4 are arange() -> identity gathers in the MLP levels.
// ---------------------------------------------------------------------------
template <int PPT, int NT>
__global__ __launch_bounds__(NT, 4) void fps_kernel(
    const float* __restrict__ pts,  // [B][n_in][stride], xyz at channels 0..2
    int stride, int npoints,
    int* __restrict__ idx_out)      // [B][npoints]
{
    constexpr int NWAVES = NT / 64;
    constexpr int N_IN   = PPT * NT;
    constexpr int NPAIR  = PPT / 2;
    constexpr int LOGNT  = (NT == 1024) ? 10 : (NT == 512) ? 9 : 8;

    const int batch = blockIdx.x;
    const int tid   = threadIdx.x;
    const int lane  = tid & 63;
    const int wv    = tid >> 6;

    const float* base = pts + (size_t)batch * N_IN * stride;
    int* iout = idx_out + (size_t)batch * npoints;

    __shared__ uint2  s_pk[2][NWAVES];   // {hi32 of winner value, winner idx}
    __shared__ float4 s_c[2][NWAVES];    // {x, y, z, lo32-as-float}
    __shared__ int    s_hist[4096];      // npoints <= 4096

    f32x2  pcx[NPAIR], pcy[NPAIR], pcz[NPAIR];
    double md[PPT];
    float  th[PPT];

#pragma unroll
    for (int k = 0; k < NPAIR; ++k) {
        int p0 = (2 * k) * NT + tid;
        int p1 = (2 * k + 1) * NT + tid;
        const float* r0 = base + (size_t)p0 * stride;
        const float* r1 = base + (size_t)p1 * stride;
        pcx[k] = f32x2{r0[0], r1[0]};
        pcy[k] = f32x2{r0[1], r1[1]};
        pcz[k] = f32x2{r0[2], r1[2]};
    }

    // first selected point is index 0
    float q0x = base[0], q0y = base[1], q0z = base[2];
    if (tid == 0) s_hist[0] = 0;

#pragma unroll
    for (int j = 0; j < PPT; ++j) {
        float x = pcx[j / 2][j & 1], y = pcy[j / 2][j & 1], z = pcz[j / 2][j & 1];
        md[j] = dist2d(x, y, z, (double)q0x, (double)q0y, (double)q0z);
        th[j] = __fmul_rn((float)md[j], 1.000004f);
    }

    // per-lane top-1 / top-2 state (keep-first => min slot index on ties)
    double bv = -1.0, b2v = -1.0;
    int    bj = 0,    b2j = 0;
    float  bx = 0.f, by = 0.f, bz = 0.f;
    float  b2x = 0.f, b2y = 0.f, b2z = 0.f;
    bool   dirty = false;

    auto scan12 = [&]() {
        bv = -1.0; bj = 0;
#pragma unroll
        for (int j = 0; j < PPT; ++j) {
            float x = pcx[j / 2][j & 1], y = pcy[j / 2][j & 1], z = pcz[j / 2][j & 1];
            if (md[j] > bv) { bv = md[j]; bj = j; bx = x; by = y; bz = z; }
        }
        b2v = -1.0; b2j = 0;
#pragma unroll
        for (int j = 0; j < PPT; ++j) {
            float x = pcx[j / 2][j & 1], y = pcy[j / 2][j & 1], z = pcz[j / 2][j & 1];
            if ((j != bj) && (md[j] > b2v)) { b2v = md[j]; b2j = j; b2x = x; b2y = y; b2z = z; }
        }
        dirty = false;
    };

    auto rebuild2 = [&]() {
        b2v = -1.0; b2j = 0;
#pragma unroll
        for (int j = 0; j < PPT; ++j) {
            float x = pcx[j / 2][j & 1], y = pcy[j / 2][j & 1], z = pcz[j / 2][j & 1];
            if ((j != bj) && (md[j] > b2v)) { b2v = md[j]; b2j = j; b2x = x; b2y = y; b2z = z; }
        }
        dirty = false;
    };

    bool pubA = false, pubB = false;   // parity 0 / 1 current?
    bool iwrote = false;               // this lane wrote the last reduce

    auto wave_reduce_publish = [&](int wp) {
        unsigned hi  = (unsigned)__double2hiint(bv);
        unsigned lo  = (unsigned)__double2loint(bv);
        int      idx = (bj << LOGNT) + tid;
        unsigned mx  = (unsigned)__builtin_amdgcn_readlane((int)wave_umax64(hi), 63);
        int wl = pick_lane(__ballot(hi == mx), lo, idx);
        iwrote = (lane == wl);
        if (iwrote) {
            s_pk[wp][wv] = make_uint2(hi, (unsigned)idx);
            s_c[wp][wv]  = make_float4(bx, by, bz, __uint_as_float(lo));
        }
    };

    scan12();
    // initial reduce; winner lane publishes BOTH parities (no readers yet)
    {
        unsigned hi  = (unsigned)__double2hiint(bv);
        unsigned lo  = (unsigned)__double2loint(bv);
        int      idx = (bj << LOGNT) + tid;
        unsigned mx  = (unsigned)__builtin_amdgcn_readlane((int)wave_umax64(hi), 63);
        int wl = pick_lane(__ballot(hi == mx), lo, idx);
        iwrote = (lane == wl);
        if (iwrote) {
            s_pk[0][wv] = make_uint2(hi, (unsigned)idx);
            s_c[0][wv]  = make_float4(bx, by, bz, __uint_as_float(lo));
            s_pk[1][wv] = s_pk[0][wv];
            s_c[1][wv]  = s_c[0][wv];
        }
        pubA = true; pubB = true;
    }

    for (int i = 1; i < npoints; ++i) {
        const int par = i & 1;

        // ---- phase 1: catch-up publish for this parity if stale ----
        bool pubCur = par ? pubB : pubA;
        if (!pubCur) {
            if (iwrote) {   // regs unchanged since the reduce that cleared the flag
                unsigned hi  = (unsigned)__double2hiint(bv);
                unsigned lo  = (unsigned)__double2loint(bv);
                int      idx = (bj << LOGNT) + tid;
                s_pk[par][wv] = make_uint2(hi, (unsigned)idx);
                s_c[par][wv]  = make_float4(bx, by, bz, __uint_as_float(lo));
            }
            if (par) pubB = true; else pubA = true;
        }
        __syncthreads();   // no outstanding vmem in-loop -> vmcnt drain free

        // ---- phase 2: reduce NWAVES partials; loads masked to lane<NWAVES ----
        unsigned phi = 0u, pidx = 0u;
        float pqx = 0.f, pqy = 0.f, pqz = 0.f, plo = 0.f;
        if (lane < NWAVES) {
            uint2  pk = s_pk[par][lane];
            float4 pc = s_c[par][lane];
            phi = pk.x; pidx = pk.y;
            pqx = pc.x; pqy = pc.y; pqz = pc.z; plo = pc.w;
        }
        // shadow work: rebuild dirty top-2 under the ds_read latency
        if (__any(dirty)) { if (dirty) rebuild2(); }

        unsigned v2 = phi;   // lanes >= NWAVES hold 0
        v2 = max(v2, dpp_u32_keep<0x111>(v2));
        v2 = max(v2, dpp_u32_keep<0x112>(v2));
        if constexpr (NWAVES >= 8)  v2 = max(v2, dpp_u32_keep<0x114>(v2));
        if constexpr (NWAVES >= 16) v2 = max(v2, dpp_u32_keep<0x118>(v2));
        unsigned ghi = (unsigned)__builtin_amdgcn_readlane((int)v2, NWAVES - 1);
        int wl2 = pick_lane(__ballot((lane < NWAVES) && (phi == ghi)),
                            (unsigned)__float_as_int(plo), (int)pidx);
        int best = __builtin_amdgcn_readlane((int)pidx, wl2);
        if (tid == 0) s_hist[i] = best;

        // winner coords via readlane (no dependent LDS read)
        const float qx = readlane_f32(pqx, wl2);
        const float qy = readlane_f32(pqy, wl2);
        const float qz = readlane_f32(pqz, wl2);
        const double qx64 = (double)qx, qy64 = (double)qy, qz64 = (double)qz;

        // ---- packed branchless screen -> wave-uniform fire mask ----
        const f32x2 nqx = {-qx, -qx}, nqy = {-qy, -qy}, nqz = {-qz, -qz};
        int fmask = 0;
#pragma unroll
        for (int k = 0; k < NPAIR; ++k) {
            f32x2 dx = pk_add(pcx[k], nqx);
            f32x2 dy = pk_add(pcy[k], nqy);
            f32x2 dz = pk_add(pcz[k], nqz);
            f32x2 d  = pk_fma(dx, dx, pk_fma(dy, dy, pk_mul(dz, dz)));
            fmask |= (__any(d.x < th[2 * k])     ? (1 << (2 * k))     : 0);
            fmask |= (__any(d.y < th[2 * k + 1]) ? (1 << (2 * k + 1)) : 0);
        }

        if (fmask) {
            bool decB = false, dec2 = false;
            double dNew = 0.0;
#pragma unroll
            for (int j = 0; j < PPT; ++j) {
                if (fmask & (1 << j)) {
                    float x = pcx[j / 2][j & 1], y = pcy[j / 2][j & 1], z = pcz[j / 2][j & 1];
                    double d   = dist2d(x, y, z, qx64, qy64, qz64);
                    double old = md[j];
                    bool dj  = (d < old);
                    bool isB = (bj == j) & dj;
                    decB = decB | isB;
                    dec2 = dec2 | ((b2j == j) & dj);
                    dNew = isB ? d : dNew;
                    md[j] = fmin(old, d);
                    th[j] = __fmul_rn((float)md[j], 1.000004f);
                }
            }
            // lazy top-1/top-2 maintenance (exact; see header proof)
            bool full    = decB & (dec2 | (dNew == b2v));
            bool promote = decB & !full & (dNew < b2v);
            bool keep    = decB & !full & !promote;    // dNew > b2v
            if (promote) { bv = b2v; bj = b2j; bx = b2x; by = b2y; bz = b2z; dirty = true; }
            if (keep)    { bv = dNew; }                 // slot/coords/t2 all stay valid
            dirty = dirty | (dec2 & !decB);
            if (__any(full)) { if (full) scan12(); }

            if (__any(decB)) {
                // some lane's top-1 changed -> re-reduce; publish NEXT parity
                wave_reduce_publish(par ^ 1);
                if (par) { pubA = true; pubB = false; }
                else     { pubB = true; pubA = false; }
            }
        }
    }

    // coalesced bulk dump of the selected indices
    __syncthreads();
    for (int k = tid; k < npoints; k += NT) iout[k] = s_hist[k];
}

// ---------------------------------------------------------------------------
// Gather + 2-layer pointwise MLP + xyz/feat concat, one kernel per level.
// IDENT=true: identity gather (FPS nesting property -> idx == arange).
// ---------------------------------------------------------------------------
template <int CIN, int F, bool REPEAT, bool IDENT>
__global__ __launch_bounds__(256) void mlp_kernel(
    const float* __restrict__ pts, int stride, int n_in,
    const int* __restrict__ idx,
    const float* __restrict__ w1, const float* __restrict__ b1,
    const float* __restrict__ w2, const float* __restrict__ b2,
    float* __restrict__ out, int np)
{
    constexpr int P    = 256 / F;
    constexpr int CINS = REPEAT ? (CIN / 2) : CIN;  // stored input channels
    constexpr int LOGF = (F == 16) ? 4 : (F == 32) ? 5 : (F == 64) ? 6 : 7;

    __shared__ float xs[P][CINS];
    __shared__ float h[P][F];

    const int tid = threadIdx.x;
    const int pl  = tid >> LOGF;       // point within block
    const int c   = tid & (F - 1);     // output channel
    const int b   = blockIdx.y;
    const int pid = blockIdx.x * P + pl;

    const int id = IDENT ? pid : idx[(size_t)b * np + pid];
    const float* row = pts + ((size_t)b * n_in + id) * stride;

    if (c < CINS) xs[pl][c] = row[c];
    __syncthreads();

    float acc = b1[c];
#pragma unroll
    for (int k = 0; k < CIN; ++k) {
        const int xk = REPEAT ? (k % 3) : k;
        acc = fmaf(xs[pl][xk], w1[k * F + c], acc);
    }
    h[pl][c] = fmaxf(acc, 0.0f);
    __syncthreads();

    float acc2 = b2[c];
#pragma unroll
    for (int f = 0; f < F; ++f)
        acc2 = fmaf(h[pl][f], w2[f * F + c], acc2);

    float res = (c < 3) ? xs[pl][c] : acc2;
    out[((size_t)b * np + pid) * (size_t)F + c] = res;
}

// ---------------------------------------------------------------------------
// Launch. Only level-1 FPS is computed; levels 2-4 are identity gathers.
// ---------------------------------------------------------------------------
extern "C" void kernel_launch(void* const* d_in, const int* in_sizes, int n_in_cnt,
                              void* d_out, int out_size, void* d_ws, size_t ws_size,
                              hipStream_t stream) {
    const float* scene = (const float*)d_in[0];
    const float* w1_1 = (const float*)d_in[1];
    const float* b1_1 = (const float*)d_in[2];
    const float* w2_1 = (const float*)d_in[3];
    const float* b2_1 = (const float*)d_in[4];
    const float* w1_2 = (const float*)d_in[5];
    const float* b1_2 = (const float*)d_in[6];
    const float* w2_2 = (const float*)d_in[7];
    const float* b2_2 = (const float*)d_in[8];
    const float* w1_3 = (const float*)d_in[9];
    const float* b1_3 = (const float*)d_in[10];
    const float* w2_3 = (const float*)d_in[11];
    const float* b2_3 = (const float*)d_in[12];
    const float* w1_4 = (const float*)d_in[13];
    const float* b1_4 = (const float*)d_in[14];
    const float* w2_4 = (const float*)d_in[15];
    const float* b2_4 = (const float*)d_in[16];

    float* out  = (float*)d_out;
    float* out1 = out;                 // [8][4096][16]
    float* out2 = out + 524288;        // [8][2048][32]
    float* out3 = out + 1048576;       // [8][1024][64]
    float* out4 = out + 1572864;       // [8][512][128]

    int* idx1 = (int*)d_ws;            // 8*4096 (only level-1 indices needed)

    const int B = 8;

    // Level 1: N=8192 -> 4096, cin=6 (repeat), F=16
    fps_kernel<8, 1024><<<B, 1024, 0, stream>>>(scene, 3, 4096, idx1);
    mlp_kernel<6, 16, true, false><<<dim3(256, B), 256, 0, stream>>>(
        scene, 3, 8192, idx1, w1_1, b1_1, w2_1, b2_1, out1, 4096);

    // Level 2: 4096 -> 2048, cin=16, F=32   (identity gather, no FPS)
    mlp_kernel<16, 32, false, true><<<dim3(256, B), 256, 0, stream>>>(
        out1, 16, 4096, nullptr, w1_2, b1_2, w2_2, b2_2, out2, 2048);

    // Level 3: 2048 -> 1024, cin=32, F=64   (identity gather, no FPS)
    mlp_kernel<32, 64, false, true><<<dim3(256, B), 256, 0, stream>>>(
        out2, 32, 2048, nullptr, w1_3, b1_3, w2_3, b2_3, out3, 1024);

    // Level 4: 1024 -> 512, cin=64, F=128   (identity gather, no FPS)
    mlp_kernel<64, 128, false, true><<<dim3(256, B), 256, 0, stream>>>(
        out3, 64, 1024, nullptr, w1_4, b1_4, w2_4, b2_4, out4, 512);
}